// Round 9
// baseline (81.368 us; speedup 1.0000x reference)
//
#include <hip/hip_runtime.h>

#define NN 2048
#define NT 256          // threads per block (4 waves)
#define NB 4
#define NC 16
#define NCLS (NB * NC)
#define TILE 64
#define NTILES (NN / TILE)
#define KKEEP 176       // >= (K-1) + 64 = 163

typedef unsigned long long u64;

// orderable(score): ascending u32 == descending score
__device__ __forceinline__ unsigned score_hi(float s) {
  unsigned u = __float_as_uint(s);
  u ^= (u >> 31) ? 0xFFFFFFFFu : 0x80000000u;  // ascending-orderable
  return ~u;                                   // descending score
}
__device__ __forceinline__ float hi_score(unsigned hiw) {
  unsigned u = ~hiw;
  unsigned bits = (u >> 31) ? (u ^ 0x80000000u) : ~u;
  return __uint_as_float(bits);
}

// IoU with the exact op order of the reference; asm guard blocks
// ffp-contract from fusing (ka + a - iw*ih) into an FMA.
__device__ __forceinline__ float iou_f(float kx1, float ky1, float kx2, float ky2, float ka,
                                       float x1, float y1, float x2, float y2, float a) {
  float ix1 = fmaxf(kx1, x1);
  float iy1 = fmaxf(ky1, y1);
  float ix2 = fminf(kx2, x2);
  float iy2 = fminf(ky2, y2);
  float iw = fmaxf(ix2 - ix1, 0.0f);
  float ih = fmaxf(iy2 - iy1, 0.0f);
  float inter = iw * ih;
  asm volatile("" : "+v"(inter));
  float denom = ka + a - inter;
  return inter / denom;
}

// compare 4 keys (one uint4) against both of this thread's elements
#define CMP4(V, J) do {                                                     \
  u64 kj;                                                                   \
  kj = ((u64)(V).x << 32) | (unsigned)((J) + 0); c0 += (kj < my0); c1 += (kj < my1); \
  kj = ((u64)(V).y << 32) | (unsigned)((J) + 1); c2 += (kj < my0); c3 += (kj < my1); \
  kj = ((u64)(V).z << 32) | (unsigned)((J) + 2); c0 += (kj < my0); c1 += (kj < my1); \
  kj = ((u64)(V).w << 32) | (unsigned)((J) + 3); c2 += (kj < my0); c3 += (kj < my1); \
} while (0)

// ---------------- kernel 1: rank sort, double-buffered LDS broadcast --------
// 256 blocks = 64 classes x 4 quarters; each thread ranks 2 elements.
// Keys = u32 orderable hi-words in LDS. Delivery = uniform ds_read_b128
// broadcast, SOFTWARE-PIPELINED: stage st+1's 4 reads are issued before
// stage st's 16-key compare block (~160 VALU cyc), covering the ~120-cycle
// LDS latency that made R8 stall (VALUBusy 35%, 1 wave/SIMD).
__global__ __launch_bounds__(NT) void rank_kernel(
    const float* __restrict__ scores,
    const float* __restrict__ boxes,
    float4* __restrict__ wbox,
    float* __restrict__ wsc, int* __restrict__ widx)
{
  __shared__ unsigned s_hi[NN];    // 8 KB

  const int blk = blockIdx.x;
  const int bc  = blk >> 2;        // class id 0..63
  const int q   = blk & 3;         // quarter
  const int b   = bc >> 4;         // batch
  const int t   = threadIdx.x;

  const float* __restrict__ scls = scores + (size_t)bc * NN;

  // stage orderable hi-words: 8 keys/thread via two float4 loads, b128 stores
  {
    const float4* s4 = (const float4*)scls;
    uint4* d4 = (uint4*)s_hi;
    float4 v = s4[t];
    d4[t] = make_uint4(score_hi(v.x), score_hi(v.y), score_hi(v.z), score_hi(v.w));
    v = s4[t + 256];
    d4[t + 256] = make_uint4(score_hi(v.x), score_hi(v.y), score_hi(v.z), score_hi(v.w));
  }
  __syncthreads();

  // my two elements
  const int i0 = q * 512 + t;
  const int i1 = i0 + 256;
  const unsigned h0 = s_hi[i0];    // per-lane stride-1: conflict-free
  const unsigned h1 = s_hi[i1];
  const u64 my0 = ((u64)h0 << 32) | (unsigned)i0;
  const u64 my1 = ((u64)h1 << 32) | (unsigned)i1;

  // rank = # keys strictly less than mine (u64 total order; keys unique)
  int c0 = 0, c1 = 0, c2 = 0, c3 = 0;
  const uint4* k4 = (const uint4*)s_hi;
  uint4 a0 = k4[0], a1 = k4[1], a2 = k4[2], a3 = k4[3];
#pragma unroll 1
  for (int st = 0; st < 127; st++) {
    const int nb = (st + 1) * 4;
    uint4 b0 = k4[nb], b1 = k4[nb + 1], b2 = k4[nb + 2], b3 = k4[nb + 3];
    const int j = st * 16;
    CMP4(a0, j); CMP4(a1, j + 4); CMP4(a2, j + 8); CMP4(a3, j + 12);
    a0 = b0; a1 = b1; a2 = b2; a3 = b3;
  }
  CMP4(a0, 2032); CMP4(a1, 2036); CMP4(a2, 2040); CMP4(a3, 2044);
  const int rank0 = c0 + c2;
  const int rank1 = c1 + c3;

  // gather boxes, fix min/max, scatter packed to sorted positions
  const float* __restrict__ bbase = boxes + (size_t)b * NN * 4;
  const size_t obase = (size_t)bc * NN;
  {
    float4 v = *(const float4*)(bbase + (size_t)i0 * 4);
    float x1 = fminf(v.x, v.z), x2 = fmaxf(v.x, v.z);
    float y1 = fminf(v.y, v.w), y2 = fmaxf(v.y, v.w);
    const size_t o = obase + rank0;
    wbox[o] = make_float4(x1, y1, x2, y2);
    wsc[o] = hi_score(h0); widx[o] = i0;
  }
  {
    float4 v = *(const float4*)(bbase + (size_t)i1 * 4);
    float x1 = fminf(v.x, v.z), x2 = fmaxf(v.x, v.z);
    float y1 = fminf(v.y, v.w), y2 = fmaxf(v.y, v.w);
    const size_t o = obase + rank1;
    wbox[o] = make_float4(x1, y1, x2, y2);
    wsc[o] = hi_score(h1); widx[o] = i1;
  }
}

// ---------------- kernel 2: per-class tiled greedy NMS ----------------
// Packed float4 boxes (1 b128 per box everywhere); tile+1 prefetched into
// registers at loop top (VMEM hides under phases); tile LDS-store by waves
// 1-3 overlaps wave 0's serial ballot resolve. 2 barriers/tile.
__global__ __launch_bounds__(NT) void greedy_kernel(
    const float4* __restrict__ wbox,
    const float* __restrict__ wsc, const int* __restrict__ widx,
    const float* __restrict__ iou_thr_p, const float* __restrict__ score_thr_p,
    int K, int* __restrict__ out)
{
  __shared__ float4 s_tb[TILE];
  __shared__ float  s_ts[TILE];
  __shared__ int    s_tidx[TILE];
  __shared__ float4 s_kbox[KKEEP];
  __shared__ float  s_ka[KKEEP];
  __shared__ u64    s_colmask[4][TILE];
  __shared__ u64    s_dead[4];
  __shared__ int    s_total;

  const int bc = blockIdx.x;
  const int b  = bc >> 4;
  const int c  = bc & 15;
  const int t  = threadIdx.x;
  const int wv = t >> 6;
  const int ln = t & 63;

  const float iou_thr = *iou_thr_p;
  const float sthr    = *score_thr_p;

  int* orow = out + (size_t)bc * K * 3;
  for (int i = t; i < K * 3; i += NT) orow[i] = -1;
  if (t == 0) s_total = 0;

  const size_t base0 = (size_t)bc * NN;

  // preload tile 0
  if      (wv == 1) s_tb[ln]   = wbox[base0 + ln];
  else if (wv == 2) s_ts[ln]   = wsc[base0 + ln];
  else if (wv == 3) s_tidx[ln] = widx[base0 + ln];
  __syncthreads();

  for (int tile = 0; tile < NTILES; tile++) {
    // own column into registers
    const float4 jb  = s_tb[ln];
    const float  jsc = s_ts[ln];
    const int    jidx = s_tidx[ln];
    const float  ja  = (jb.z - jb.x) * (jb.w - jb.y);  // reference op order
    const int kcount = s_total;    // stable: last written before prev barrier

    // prefetch tile+1 into registers (VMEM latency hides under phases)
    const int pt = (tile + 1 < NTILES) ? tile + 1 : tile;
    float4 pb; float ps = 0.f; int pi = 0;
    if      (wv == 1) pb = wbox[base0 + pt * TILE + ln];
    else if (wv == 2) ps = wsc[base0 + pt * TILE + ln];
    else if (wv == 3) pi = widx[base0 + pt * TILE + ln];

    // Phase A: intra-tile upper-triangle IoU mask (wave wv: rows wv*16..+15)
    u64 m = 0ULL;
    for (int r = 0; r < 16; r++) {
      const int il = wv * 16 + r;
      if (il < ln) {
        const float4 rb = s_tb[il];                    // b128 broadcast
        const float ra = (rb.z - rb.x) * (rb.w - rb.y);
        const float iou = iou_f(rb.x, rb.y, rb.z, rb.w, ra,
                                jb.x, jb.y, jb.z, jb.w, ja);
        if (iou > iou_thr) m |= (1ULL << il);
      }
    }
    s_colmask[wv][ln] = m;

    // dead-check vs accumulated kept list (strided by wave)
    bool dead = false;
    for (int ki = wv; ki < kcount; ki += 4) {
      const float4 kb = s_kbox[ki];                    // one b128 + one b32
      const float iou = iou_f(kb.x, kb.y, kb.z, kb.w, s_ka[ki],
                              jb.x, jb.y, jb.z, jb.w, ja);
      if (iou > iou_thr) { dead = true; break; }
    }
    s_dead[wv] = __ballot(dead);
    __syncthreads();                                   // barrier 1

    if (wv == 1)      s_tb[ln]   = pb;                 // overlap: tile store
    else if (wv == 2) s_ts[ln]   = ps;
    else if (wv == 3) s_tidx[ln] = pi;
    else {
      // wave 0: serial greedy resolve via ballots
      const u64 mc = s_colmask[0][ln] | s_colmask[1][ln] |
                     s_colmask[2][ln] | s_colmask[3][ln];
      u64 alive = ~(s_dead[0] | s_dead[1] | s_dead[2] | s_dead[3]);
      for (int i2 = 0; i2 < TILE; i2++) {
        if ((alive >> i2) & 1ULL) {
          const u64 kill = __ballot((int)((mc >> i2) & 1ULL));
          alive &= ~kill;
        }
      }
      const int total0 = s_total;
      const bool kept = (alive >> ln) & 1ULL;
      const int pos = __popcll(alive & ((1ULL << ln) - 1ULL));
      if (kept) {
        const int kpos = total0 + pos;                 // <= 99 + 63 < KKEEP
        s_kbox[kpos] = jb;
        s_ka[kpos]   = ja;
        if (kpos < K && jsc >= sthr) {
          orow[kpos * 3 + 0] = b;
          orow[kpos * 3 + 1] = c;
          orow[kpos * 3 + 2] = jidx;
        }
      }
      if (ln == 0) s_total = total0 + (int)__popcll(alive);
    }
    __syncthreads();                                   // barrier 2
    if (s_total >= K) break;   // uniform; stable until next resolve
  }
}

extern "C" void kernel_launch(void* const* d_in, const int* in_sizes, int n_in,
                              void* d_out, int out_size, void* d_ws, size_t ws_size,
                              hipStream_t stream) {
  const float* boxes  = (const float*)d_in[0];
  const float* scores = (const float*)d_in[1];
  const float* iou_p  = (const float*)d_in[3];
  const float* sth_p  = (const float*)d_in[4];
  int* out = (int*)d_out;

  const int K = out_size / (NCLS * 3);
  const size_t plane = (size_t)NCLS * NN;

  float4* wbox = (float4*)d_ws;                 // 2 MB
  float*  wsc  = (float*)(wbox + plane);
  int*    widx = (int*)(wsc + plane);

  hipLaunchKernelGGL(rank_kernel, dim3(NCLS * 4), dim3(NT), 0, stream,
                     scores, boxes, wbox, wsc, widx);
  hipLaunchKernelGGL(greedy_kernel, dim3(NCLS), dim3(NT), 0, stream,
                     wbox, wsc, widx, iou_p, sth_p, K, out);
}

// Round 10
// 60.874 us; speedup vs baseline: 1.3367x; 1.3367x over previous
//
#include <hip/hip_runtime.h>

#define NN 2048
#define NT 256          // threads per block (4 waves)
#define NB 4
#define NC 16
#define NCLS (NB * NC)
#define TILE 64
#define NTILES (NN / TILE)
#define KKEEP 176       // >= (K-1) + 64 = 163

typedef unsigned long long u64;

// orderable(score): ascending u32 == descending score
__device__ __forceinline__ unsigned score_hi(float s) {
  unsigned u = __float_as_uint(s);
  u ^= (u >> 31) ? 0xFFFFFFFFu : 0x80000000u;  // ascending-orderable
  return ~u;                                   // descending score
}
__device__ __forceinline__ float hi_score(unsigned hiw) {
  unsigned u = ~hiw;
  unsigned bits = (u >> 31) ? (u ^ 0x80000000u) : ~u;
  return __uint_as_float(bits);
}

// IoU with the exact op order of the reference; asm guard blocks
// ffp-contract from fusing (ka + a - iw*ih) into an FMA.
__device__ __forceinline__ float iou_f(float kx1, float ky1, float kx2, float ky2, float ka,
                                       float x1, float y1, float x2, float y2, float a) {
  float ix1 = fmaxf(kx1, x1);
  float iy1 = fmaxf(ky1, y1);
  float ix2 = fminf(kx2, x2);
  float iy2 = fminf(ky2, y2);
  float iw = fmaxf(ix2 - ix1, 0.0f);
  float ih = fmaxf(iy2 - iy1, 0.0f);
  float inter = iw * ih;
  asm volatile("" : "+v"(inter));
  float denom = ka + a - inter;
  return inter / denom;
}

// ---------------- kernel 1: rank sort via LDS b128 broadcast + TLP ----------
// 512 blocks = 64 classes x 8 chunks; each thread ranks ONE element.
// 2 blocks/CU -> 8 waves/CU -> 2 waves/SIMD: LDS latency hidden by TLP,
// cost = LDS-pipe throughput only (8 x 512 x 12 cyc ~ 20us chip-wide).
// No software pipelining (R9 regression: register copies + moved waits).
__global__ __launch_bounds__(NT) void rank_kernel(
    const float* __restrict__ scores,
    const float* __restrict__ boxes,
    float4* __restrict__ wbox,
    float* __restrict__ wsc, int* __restrict__ widx)
{
  __shared__ unsigned s_hi[NN];    // 8 KB

  const int blk   = blockIdx.x;
  const int bc    = blk >> 3;      // class id 0..63
  const int chunk = blk & 7;
  const int b     = bc >> 4;       // batch
  const int t     = threadIdx.x;

  const float* __restrict__ scls = scores + (size_t)bc * NN;

  // stage orderable hi-words: 8 keys/thread via two float4 loads, b128 stores
  {
    const float4* s4 = (const float4*)scls;
    uint4* d4 = (uint4*)s_hi;
    float4 v = s4[t];
    d4[t] = make_uint4(score_hi(v.x), score_hi(v.y), score_hi(v.z), score_hi(v.w));
    v = s4[t + 256];
    d4[t + 256] = make_uint4(score_hi(v.x), score_hi(v.y), score_hi(v.z), score_hi(v.w));
  }
  __syncthreads();

  // my element
  const int i0 = chunk * NT + t;
  const unsigned h0 = s_hi[i0];    // per-lane stride-1: conflict-free
  const u64 my0 = ((u64)h0 << 32) | (unsigned)i0;

  // rank = # keys strictly less than mine (u64 total order; keys unique)
  int c0 = 0, c1 = 0;
  const uint4* k4 = (const uint4*)s_hi;
#pragma unroll 2
  for (int jc = 0; jc < NN / 4; jc++) {
    const uint4 ka = k4[jc];       // uniform addr -> b128 broadcast
    const int j = jc * 4;
    u64 kj;
    kj = ((u64)ka.x << 32) | (unsigned)(j + 0); c0 += (kj < my0);
    kj = ((u64)ka.y << 32) | (unsigned)(j + 1); c1 += (kj < my0);
    kj = ((u64)ka.z << 32) | (unsigned)(j + 2); c0 += (kj < my0);
    kj = ((u64)ka.w << 32) | (unsigned)(j + 3); c1 += (kj < my0);
  }
  const int rank0 = c0 + c1;

  // gather my box, fix min/max, scatter packed to sorted position
  const float* __restrict__ bbase = boxes + (size_t)b * NN * 4;
  {
    float4 v = *(const float4*)(bbase + (size_t)i0 * 4);
    float x1 = fminf(v.x, v.z), x2 = fmaxf(v.x, v.z);
    float y1 = fminf(v.y, v.w), y2 = fmaxf(v.y, v.w);
    const size_t o = (size_t)bc * NN + rank0;
    wbox[o] = make_float4(x1, y1, x2, y2);
    wsc[o] = hi_score(h0); widx[o] = i0;
  }
}

// ---------------- kernel 2: per-class tiled greedy NMS ----------------
// Packed float4 boxes (1 b128 per box everywhere); tile+1 prefetched into
// registers at loop top (VMEM hides under phases); tile LDS-store by waves
// 1-3 overlaps wave 0's serial ballot resolve. 2 barriers/tile.
__global__ __launch_bounds__(NT) void greedy_kernel(
    const float4* __restrict__ wbox,
    const float* __restrict__ wsc, const int* __restrict__ widx,
    const float* __restrict__ iou_thr_p, const float* __restrict__ score_thr_p,
    int K, int* __restrict__ out)
{
  __shared__ float4 s_tb[TILE];
  __shared__ float  s_ts[TILE];
  __shared__ int    s_tidx[TILE];
  __shared__ float4 s_kbox[KKEEP];
  __shared__ float  s_ka[KKEEP];
  __shared__ u64    s_colmask[4][TILE];
  __shared__ u64    s_dead[4];
  __shared__ int    s_total;

  const int bc = blockIdx.x;
  const int b  = bc >> 4;
  const int c  = bc & 15;
  const int t  = threadIdx.x;
  const int wv = t >> 6;
  const int ln = t & 63;

  const float iou_thr = *iou_thr_p;
  const float sthr    = *score_thr_p;

  int* orow = out + (size_t)bc * K * 3;
  for (int i = t; i < K * 3; i += NT) orow[i] = -1;
  if (t == 0) s_total = 0;

  const size_t base0 = (size_t)bc * NN;

  // preload tile 0
  if      (wv == 1) s_tb[ln]   = wbox[base0 + ln];
  else if (wv == 2) s_ts[ln]   = wsc[base0 + ln];
  else if (wv == 3) s_tidx[ln] = widx[base0 + ln];
  __syncthreads();

  for (int tile = 0; tile < NTILES; tile++) {
    // own column into registers
    const float4 jb  = s_tb[ln];
    const float  jsc = s_ts[ln];
    const int    jidx = s_tidx[ln];
    const float  ja  = (jb.z - jb.x) * (jb.w - jb.y);  // reference op order
    const int kcount = s_total;    // stable: last written before prev barrier

    // prefetch tile+1 into registers (VMEM latency hides under phases)
    const int pt = (tile + 1 < NTILES) ? tile + 1 : tile;
    float4 pb; float ps = 0.f; int pi = 0;
    if      (wv == 1) pb = wbox[base0 + pt * TILE + ln];
    else if (wv == 2) ps = wsc[base0 + pt * TILE + ln];
    else if (wv == 3) pi = widx[base0 + pt * TILE + ln];

    // Phase A: intra-tile upper-triangle IoU mask (wave wv: rows wv*16..+15)
    u64 m = 0ULL;
    for (int r = 0; r < 16; r++) {
      const int il = wv * 16 + r;
      if (il < ln) {
        const float4 rb = s_tb[il];                    // b128 broadcast
        const float ra = (rb.z - rb.x) * (rb.w - rb.y);
        const float iou = iou_f(rb.x, rb.y, rb.z, rb.w, ra,
                                jb.x, jb.y, jb.z, jb.w, ja);
        if (iou > iou_thr) m |= (1ULL << il);
      }
    }
    s_colmask[wv][ln] = m;

    // dead-check vs accumulated kept list (strided by wave)
    bool dead = false;
    for (int ki = wv; ki < kcount; ki += 4) {
      const float4 kb = s_kbox[ki];                    // one b128 + one b32
      const float iou = iou_f(kb.x, kb.y, kb.z, kb.w, s_ka[ki],
                              jb.x, jb.y, jb.z, jb.w, ja);
      if (iou > iou_thr) { dead = true; break; }
    }
    s_dead[wv] = __ballot(dead);
    __syncthreads();                                   // barrier 1

    if (wv == 1)      s_tb[ln]   = pb;                 // overlap: tile store
    else if (wv == 2) s_ts[ln]   = ps;
    else if (wv == 3) s_tidx[ln] = pi;
    else {
      // wave 0: serial greedy resolve via ballots
      const u64 mc = s_colmask[0][ln] | s_colmask[1][ln] |
                     s_colmask[2][ln] | s_colmask[3][ln];
      u64 alive = ~(s_dead[0] | s_dead[1] | s_dead[2] | s_dead[3]);
      for (int i2 = 0; i2 < TILE; i2++) {
        if ((alive >> i2) & 1ULL) {
          const u64 kill = __ballot((int)((mc >> i2) & 1ULL));
          alive &= ~kill;
        }
      }
      const int total0 = s_total;
      const bool kept = (alive >> ln) & 1ULL;
      const int pos = __popcll(alive & ((1ULL << ln) - 1ULL));
      if (kept) {
        const int kpos = total0 + pos;                 // <= 99 + 63 < KKEEP
        s_kbox[kpos] = jb;
        s_ka[kpos]   = ja;
        if (kpos < K && jsc >= sthr) {
          orow[kpos * 3 + 0] = b;
          orow[kpos * 3 + 1] = c;
          orow[kpos * 3 + 2] = jidx;
        }
      }
      if (ln == 0) s_total = total0 + (int)__popcll(alive);
    }
    __syncthreads();                                   // barrier 2
    if (s_total >= K) break;   // uniform; stable until next resolve
  }
}

extern "C" void kernel_launch(void* const* d_in, const int* in_sizes, int n_in,
                              void* d_out, int out_size, void* d_ws, size_t ws_size,
                              hipStream_t stream) {
  const float* boxes  = (const float*)d_in[0];
  const float* scores = (const float*)d_in[1];
  const float* iou_p  = (const float*)d_in[3];
  const float* sth_p  = (const float*)d_in[4];
  int* out = (int*)d_out;

  const int K = out_size / (NCLS * 3);
  const size_t plane = (size_t)NCLS * NN;

  float4* wbox = (float4*)d_ws;                 // 2 MB
  float*  wsc  = (float*)(wbox + plane);
  int*    widx = (int*)(wsc + plane);

  hipLaunchKernelGGL(rank_kernel, dim3(NCLS * 8), dim3(NT), 0, stream,
                     scores, boxes, wbox, wsc, widx);
  hipLaunchKernelGGL(greedy_kernel, dim3(NCLS), dim3(NT), 0, stream,
                     wbox, wsc, widx, iou_p, sth_p, K, out);
}